// Round 1
// 312.812 us; speedup vs baseline: 1.2117x; 1.2117x over previous
//
#include <hip/hip_runtime.h>

typedef _Float16 f16x8 __attribute__((ext_vector_type(8)));
typedef _Float16 f16x4 __attribute__((ext_vector_type(4)));
typedef float f32x4 __attribute__((ext_vector_type(4)));

#define PADB 16     // pad bucket counters: one per 64B line
#define MAXNB 512   // max buckets (N <= 131072, bucket = 256 nodes)
#define TILE_A 4096 // edges per binning tile

__device__ __forceinline__ float lrelu(float v) { return v >= 0.f ? v : 0.2f * v; }
// clamped exp: identical softmax ratios unless logits >60 (never for this data)
__device__ __forceinline__ float cexp(float v) { return expf(fminf(v, 60.f)); }
// fast tanh: (e^2x-1)/(e^2x+1); clamp avoids overflow, e->0 handles -inf side
__device__ __forceinline__ float ftanh(float x) {
    float e = __expf(fminf(2.f * x, 30.f));
    return (e - 1.f) / (e + 1.f);
}

// ---- fused prep: blocks 0,1 build Al/Ar + Wt fp16 per layer; block 2 zeros
// the (tiny, padded) bucket counters ----------------------------------------
__global__ __launch_bounds__(256) void k_wprep(
    const float* __restrict__ W1, const float* __restrict__ al1, const float* __restrict__ ar1,
    const float* __restrict__ W2, const float* __restrict__ al2, const float* __restrict__ ar2,
    float* __restrict__ A1l, float* __restrict__ A1r,
    float* __restrict__ A2l, float* __restrict__ A2r,
    _Float16* __restrict__ Wt1, _Float16* __restrict__ Wt2,
    int* __restrict__ bktc, int nb)
{
    int b = blockIdx.x, t = threadIdx.x;
    if (b < 2) {
        const float* W  = b ? W2 : W1;
        const float* al = b ? al2 : al1;
        const float* ar = b ? ar2 : ar1;
        float* Al = b ? A2l : A1l;
        float* Ar = b ? A2r : A1r;
        _Float16* Wt = b ? Wt2 : Wt1;
        int k = t >> 2, h = t & 3;
        float sl = 0.f, sr = 0.f;
#pragma unroll 8
        for (int f = 0; f < 64; ++f) {
            float wv = W[k * 256 + h * 64 + f];
            sl = fmaf(wv, al[h * 64 + f], sl);
            sr = fmaf(wv, ar[h * 64 + f], sr);
        }
        Al[k * 4 + h] = sl;
        Ar[k * 4 + h] = sr;
        int col = t;
#pragma unroll 8
        for (int kk = 0; kk < 64; ++kk)
            Wt[col * 64 + kk] = (_Float16)W[kk * 256 + col];
    } else {
        for (int i = t; i < nb; i += 256) bktc[(size_t)i * PADB] = 0;
    }
}

// ---- fused: blocks [0,eb) LDS bucket-histogram of dst; rest: layer-1 el/er -
__global__ __launch_bounds__(256) void k_elr_hist(
    const float* __restrict__ Xf, _Float16* __restrict__ XhOut,
    const float* __restrict__ Al, const float* __restrict__ Ar,
    float* __restrict__ el, float* __restrict__ er, int nNodes,
    const int* __restrict__ dst, int* __restrict__ bktc, int E_, int ebBlocks,
    int nb)
{
    int b = blockIdx.x;
    if (b < ebBlocks) {
        __shared__ int lb[MAXNB];
        int t = threadIdx.x;
        for (int i = t; i < nb; i += 256) lb[i] = 0;
        __syncthreads();
        int base = b * TILE_A;
        int end = base + TILE_A; if (end > E_) end = E_;
        for (int j = base + t; j < end; j += 256)
            atomicAdd(&lb[((unsigned)dst[j]) >> 8], 1);
        __syncthreads();
        for (int i = t; i < nb; i += 256) {
            int c = lb[i];
            if (c) atomicAdd(&bktc[(size_t)i * PADB], c);
        }
        return;
    }
    int lane = threadIdx.x & 63, wid = threadIdx.x >> 6;
    int q = lane >> 4, c = lane & 15;
    int n = (b - ebBlocks) * 16 + wid * 4 + q;
    if (n >= nNodes) return;  // uniform within each 16-lane quarter
    float4 xv = *reinterpret_cast<const float4*>(Xf + (size_t)n * 64 + c * 4);
    f16x4 xh4 = {(_Float16)xv.x, (_Float16)xv.y, (_Float16)xv.z, (_Float16)xv.w};
    *reinterpret_cast<f16x4*>(XhOut + (size_t)n * 64 + c * 4) = xh4;
    float p0 = 0.f, p1 = 0.f, p2 = 0.f, p3 = 0.f;
    float q0 = 0.f, q1 = 0.f, q2 = 0.f, q3 = 0.f;
    float xs[4] = {xv.x, xv.y, xv.z, xv.w};
#pragma unroll
    for (int i = 0; i < 4; ++i) {
        float4 av = *reinterpret_cast<const float4*>(Al + (c * 4 + i) * 4);
        float4 rv = *reinterpret_cast<const float4*>(Ar + (c * 4 + i) * 4);
        p0 = fmaf(xs[i], av.x, p0); p1 = fmaf(xs[i], av.y, p1);
        p2 = fmaf(xs[i], av.z, p2); p3 = fmaf(xs[i], av.w, p3);
        q0 = fmaf(xs[i], rv.x, q0); q1 = fmaf(xs[i], rv.y, q1);
        q2 = fmaf(xs[i], rv.z, q2); q3 = fmaf(xs[i], rv.w, q3);
    }
#pragma unroll
    for (int m = 1; m <= 8; m <<= 1) {
        p0 += __shfl_xor(p0, m, 64); p1 += __shfl_xor(p1, m, 64);
        p2 += __shfl_xor(p2, m, 64); p3 += __shfl_xor(p3, m, 64);
        q0 += __shfl_xor(q0, m, 64); q1 += __shfl_xor(q1, m, 64);
        q2 += __shfl_xor(q2, m, 64); q3 += __shfl_xor(q3, m, 64);
    }
    if (c == 0) {
        *reinterpret_cast<float4*>(el + (size_t)n * 4) = make_float4(p0, p1, p2, p3);
        *reinterpret_cast<float4*>(er + (size_t)n * 4) = make_float4(q0, q1, q2, q3);
    }
}

// ---- layer-2 el/er from fp16 h1, quarter-wave per node --------------------
__global__ __launch_bounds__(256) void k_elr2(
    const _Float16* __restrict__ Xh,
    const float* __restrict__ Al, const float* __restrict__ Ar,
    float* __restrict__ el, float* __restrict__ er, int nNodes)
{
    int lane = threadIdx.x & 63, wid = threadIdx.x >> 6;
    int q = lane >> 4, c = lane & 15;
    int n = blockIdx.x * 16 + wid * 4 + q;
    if (n >= nNodes) return;
    f16x4 xh4 = *reinterpret_cast<const f16x4*>(Xh + (size_t)n * 64 + c * 4);
    float p0 = 0.f, p1 = 0.f, p2 = 0.f, p3 = 0.f;
    float q0 = 0.f, q1 = 0.f, q2 = 0.f, q3 = 0.f;
#pragma unroll
    for (int i = 0; i < 4; ++i) {
        float xs = (float)xh4[i];
        float4 av = *reinterpret_cast<const float4*>(Al + (c * 4 + i) * 4);
        float4 rv = *reinterpret_cast<const float4*>(Ar + (c * 4 + i) * 4);
        p0 = fmaf(xs, av.x, p0); p1 = fmaf(xs, av.y, p1);
        p2 = fmaf(xs, av.z, p2); p3 = fmaf(xs, av.w, p3);
        q0 = fmaf(xs, rv.x, q0); q1 = fmaf(xs, rv.y, q1);
        q2 = fmaf(xs, rv.z, q2); q3 = fmaf(xs, rv.w, q3);
    }
#pragma unroll
    for (int m = 1; m <= 8; m <<= 1) {
        p0 += __shfl_xor(p0, m, 64); p1 += __shfl_xor(p1, m, 64);
        p2 += __shfl_xor(p2, m, 64); p3 += __shfl_xor(p3, m, 64);
        q0 += __shfl_xor(q0, m, 64); q1 += __shfl_xor(q1, m, 64);
        q2 += __shfl_xor(q2, m, 64); q3 += __shfl_xor(q3, m, 64);
    }
    if (c == 0) {
        *reinterpret_cast<float4*>(el + (size_t)n * 4) = make_float4(p0, p1, p2, p3);
        *reinterpret_cast<float4*>(er + (size_t)n * 4) = make_float4(q0, q1, q2, q3);
    }
}

// ---- single-wave exclusive scan of bucket counts -> bases + cursors -------
__global__ void k_bscan(const int* __restrict__ bktc, int* __restrict__ bbase,
                        int* __restrict__ bcur, int nb) {
    int lane = threadIdx.x;
    int carry = 0;
    for (int base = 0; base < nb; base += 64) {
        int i = base + lane;
        int v = (i < nb) ? bktc[(size_t)i * PADB] : 0;
        int sc = v;
#pragma unroll
        for (int d = 1; d < 64; d <<= 1) {
            int u = __shfl_up(sc, d, 64);
            if (lane >= d) sc += u;
        }
        if (i < nb) {
            int ex = carry + sc - v;
            bbase[i] = ex;
            bcur[(size_t)i * PADB] = ex;
        }
        carry += __shfl(sc, 63, 64);
    }
    if (lane == 0) bbase[nb] = carry;
}

// ---- binA: partition edges into dst>>8 buckets, LDS-staged for coalescing -
// packs (src | dstlo<<17); valid while N < 131072
__global__ __launch_bounds__(256) void k_binA(
    const int* __restrict__ src, const int* __restrict__ dst,
    int* __restrict__ bcur, unsigned* __restrict__ ebkt, int E_, int nb)
{
    __shared__ int lcnt[MAXNB];
    __shared__ int lcur[MAXNB];
    __shared__ int lofs[MAXNB];
    __shared__ int gbase[MAXNB];
    __shared__ unsigned spack[TILE_A];
    __shared__ int gposs[TILE_A];
    int t = threadIdx.x;
    int tile0 = blockIdx.x * TILE_A;
    int cntT = E_ - tile0; if (cntT > TILE_A) cntT = TILE_A;

    for (int i = t; i < nb; i += 256) { lcnt[i] = 0; lcur[i] = 0; }
    __syncthreads();

    int myS[16], myD[16];
#pragma unroll
    for (int k = 0; k < 16; ++k) {
        int idx = k * 256 + t;
        if (idx < cntT) {
            myS[k] = src[tile0 + idx];
            myD[k] = dst[tile0 + idx];
            atomicAdd(&lcnt[((unsigned)myD[k]) >> 8], 1);
        }
    }
    __syncthreads();

    // reserve output space per bucket (one global atomic per tile x bucket)
    for (int i = t; i < nb; i += 256) {
        int c = lcnt[i];
        gbase[i] = c ? atomicAdd(&bcur[(size_t)i * PADB], c) : 0;
    }
    // exclusive scan of lcnt -> lofs (wave 0)
    if (t < 64) {
        int carry = 0;
        for (int base = 0; base < nb; base += 64) {
            int i = base + t;
            int v = (i < nb) ? lcnt[i] : 0;
            int sc = v;
#pragma unroll
            for (int d = 1; d < 64; d <<= 1) {
                int u = __shfl_up(sc, d, 64);
                if (t >= d) sc += u;
            }
            if (i < nb) lofs[i] = carry + sc - v;
            carry += __shfl(sc, 63, 64);
        }
    }
    __syncthreads();

    // group the tile's edges by bucket in LDS, remember global dest
#pragma unroll
    for (int k = 0; k < 16; ++k) {
        int idx = k * 256 + t;
        if (idx < cntT) {
            int b = ((unsigned)myD[k]) >> 8;
            int slot = atomicAdd(&lcur[b], 1);
            int lidx = lofs[b] + slot;
            spack[lidx] = (unsigned)myS[k] | (((unsigned)myD[k] & 255u) << 17);
            gposs[lidx] = gbase[b] + slot;
        }
    }
    __syncthreads();

    // write out: consecutive staged entries -> consecutive global addresses
    for (int j = t; j < cntT; j += 256)
        ebkt[gposs[j]] = spack[j];
}

// ---- binC: per-bucket node-degree counts (plain writes, no global atomics) -
__global__ __launch_bounds__(256) void k_binC(
    const unsigned* __restrict__ ebkt, const int* __restrict__ bbase,
    int* __restrict__ cnt, int nNodes)
{
    __shared__ int lc[256];
    int b = blockIdx.x, t = threadIdx.x;
    lc[t] = 0;
    __syncthreads();
    int s0 = bbase[b], s1 = bbase[b + 1];
    for (int j = s0 + t; j < s1; j += 256)
        atomicAdd(&lc[ebkt[j] >> 17], 1);
    __syncthreads();
    int node = (b << 8) + t;
    if (node < nNodes) cnt[node] = lc[t];
}

// ---- binB: final in-bucket scatter; writes land in a ~10KB hot window -----
__global__ __launch_bounds__(256) void k_binB(
    const unsigned* __restrict__ ebkt, const int* __restrict__ bbase,
    const int* __restrict__ offs, int* __restrict__ esrc, int nNodes)
{
    __shared__ int lcur[256];
    __shared__ int lofs[256];
    int b = blockIdx.x, t = threadIdx.x;
    lcur[t] = 0;
    int node = (b << 8) + t;
    lofs[t] = (node < nNodes) ? offs[node] : 0;
    __syncthreads();
    int s0 = bbase[b], s1 = bbase[b + 1];
    for (int j = s0 + t; j < s1; j += 256) {
        unsigned v = ebkt[j];
        int dl = v >> 17;
        int p = lofs[dl] + atomicAdd(&lcur[dl], 1);
        esrc[p] = (int)(v & 0x1FFFFu);
    }
}

// ---------------- CSR scan (unpadded cnt) -------------------
#define SC_VPT 8
#define SC_CHUNK 2048  // 256 threads * 8

__global__ __launch_bounds__(256) void k_chunk_sums(const int* __restrict__ cnt,
                                                    int* __restrict__ bsums, int n) {
    int tid = threadIdx.x;
    int base = blockIdx.x * SC_CHUNK + tid * SC_VPT;
    int s = 0;
#pragma unroll
    for (int i = 0; i < SC_VPT; ++i) { int idx = base + i; if (idx < n) s += cnt[idx]; }
#pragma unroll
    for (int m = 1; m < 64; m <<= 1) s += __shfl_xor(s, m, 64);
    int lane = tid & 63, wid = tid >> 6;
    __shared__ int sh[4];
    if (lane == 0) sh[wid] = s;
    __syncthreads();
    if (tid == 0) bsums[blockIdx.x] = sh[0] + sh[1] + sh[2] + sh[3];
}

// wave-parallel exclusive scan of bsums
__global__ void k_scan_mid(int* bsums, int nb) {
    int lane = threadIdx.x & 63;
    int carry = 0;
    for (int base = 0; base < nb; base += 64) {
        int i = base + lane;
        int v = (i < nb) ? bsums[i] : 0;
        int sc = v;
#pragma unroll
        for (int d = 1; d < 64; d <<= 1) {
            int t = __shfl_up(sc, d, 64);
            if (lane >= d) sc += t;
        }
        if (i < nb) bsums[i] = carry + sc - v;
        carry += __shfl(sc, 63, 64);
    }
}

__global__ __launch_bounds__(256) void k_scan_write(const int* __restrict__ cnt,
                                                    const int* __restrict__ bsums,
                                                    int* __restrict__ offs, int n) {
    int tid = threadIdx.x;
    int base = blockIdx.x * SC_CHUNK + tid * SC_VPT;
    int v[SC_VPT]; int s = 0;
#pragma unroll
    for (int i = 0; i < SC_VPT; ++i) { int idx = base + i; v[i] = (idx < n) ? cnt[idx] : 0; s += v[i]; }
    int lane = tid & 63, wid = tid >> 6;
    int sc = s;
#pragma unroll
    for (int d = 1; d < 64; d <<= 1) { int t = __shfl_up(sc, d, 64); if (lane >= d) sc += t; }
    __shared__ int wsum[4];
    if (lane == 63) wsum[wid] = sc;
    __syncthreads();
    int wbase = 0;
    for (int i = 0; i < wid; ++i) wbase += wsum[i];
    int p = bsums[blockIdx.x] + wbase + (sc - s);
#pragma unroll
    for (int i = 0; i < SC_VPT; ++i) {
        int idx = base + i;
        if (idx < n) {
            offs[idx] = p; p += v[i];
            if (idx == n - 1) offs[n] = p;
        }
    }
}

// ---- fused softmax-stats + gather: QUARTER-WAVE per node -------------------
__global__ __launch_bounds__(256) void k_sg(
    const int* __restrict__ esrc, const int* __restrict__ offs,
    const float* __restrict__ el, const float* __restrict__ er,
    const _Float16* __restrict__ Xh, _Float16* __restrict__ agg, int nNodes)
{
    int lane = threadIdx.x & 63, wid = threadIdx.x >> 6;
    int q = lane >> 4, c = lane & 15, c4 = c * 4;
    int n = blockIdx.x * 16 + wid * 4 + q;
    if (n >= nNodes) return;  // uniform within quarter
    int s0 = offs[n], s1 = offs[n + 1];
    int d = s1 - s0;
    _Float16* aggr = agg + (size_t)n * 256;
    float4 erv = *reinterpret_cast<const float4*>(er + (size_t)n * 4);

    // ---- stats (no max-pass): chunk 0 (16 edges) cached in registers ----
    int sreg = 0;
    float x0 = 0.f, x1 = 0.f, x2 = 0.f, x3 = 0.f;
    if (c < d) {
        sreg = esrc[s0 + c];
        float4 v = *reinterpret_cast<const float4*>(el + (size_t)sreg * 4);
        x0 = cexp(lrelu(v.x + erv.x)); x1 = cexp(lrelu(v.y + erv.y));
        x2 = cexp(lrelu(v.z + erv.z)); x3 = cexp(lrelu(v.w + erv.w));
    }
    float t0 = x0, t1 = x1, t2 = x2, t3 = x3;
    for (int j = s0 + c + 16; j < s1; j += 16) {   // deg > 16 (rare)
        int s = esrc[j];
        float4 v = *reinterpret_cast<const float4*>(el + (size_t)s * 4);
        t0 += cexp(lrelu(v.x + erv.x)); t1 += cexp(lrelu(v.y + erv.y));
        t2 += cexp(lrelu(v.z + erv.z)); t3 += cexp(lrelu(v.w + erv.w));
    }
#pragma unroll
    for (int m = 1; m <= 8; m <<= 1) {   // reduce within quarter
        t0 += __shfl_xor(t0, m, 64); t1 += __shfl_xor(t1, m, 64);
        t2 += __shfl_xor(t2, m, 64); t3 += __shfl_xor(t3, m, 64);
    }
    float i0 = 1.f / t0, i1 = 1.f / t1, i2 = 1.f / t2, i3 = 1.f / t3;
    float a0 = x0 * i0, a1 = x1 * i1, a2 = x2 * i2, a3 = x3 * i3; // alpha, edge s0+c

    // ---- gather: chunks of 16 edges; rounds of 4 edges, 4 indep loads ----
    float A0[4] = {}, A1[4] = {}, A2[4] = {}, A3[4] = {};
    int base = s0;
    bool first = true;
    while (base < s1) {
        int cnt_ = s1 - base; if (cnt_ > 16) cnt_ = 16;
        int sj; float w0, w1, w2, w3;
        if (first) { sj = sreg; w0 = a0; w1 = a1; w2 = a2; w3 = a3; }
        else {
            sj = 0; w0 = w1 = w2 = w3 = 0.f;
            if (c < cnt_) {
                sj = esrc[base + c];
                float4 v = *reinterpret_cast<const float4*>(el + (size_t)sj * 4);
                w0 = cexp(lrelu(v.x + erv.x)) * i0;
                w1 = cexp(lrelu(v.y + erv.y)) * i1;
                w2 = cexp(lrelu(v.z + erv.z)) * i2;
                w3 = cexp(lrelu(v.w + erv.w)) * i3;
            }
        }
        int rnd = (cnt_ + 3) & ~3;
        for (int b = 0; b < rnd; b += 4) {
            int ss[4];
            float q0[4], q1[4], q2[4], q3[4];
            f16x4 xv[4];
#pragma unroll
            for (int u = 0; u < 4; ++u) {
                int jj = q * 16 + b + u;            // lane holding edge b+u of this quarter
                ss[u] = __shfl(sj, jj, 64);
                q0[u] = __shfl(w0, jj, 64); q1[u] = __shfl(w1, jj, 64);
                q2[u] = __shfl(w2, jj, 64); q3[u] = __shfl(w3, jj, 64);
            }
#pragma unroll
            for (int u = 0; u < 4; ++u)
                xv[u] = *reinterpret_cast<const f16x4*>(Xh + (size_t)ss[u] * 64 + c4);
#pragma unroll
            for (int u = 0; u < 4; ++u) {
#pragma unroll
                for (int i = 0; i < 4; ++i) {
                    float xf = (float)xv[u][i];
                    A0[i] = fmaf(q0[u], xf, A0[i]);
                    A1[i] = fmaf(q1[u], xf, A1[i]);
                    A2[i] = fmaf(q2[u], xf, A2[i]);
                    A3[i] = fmaf(q3[u], xf, A3[i]);
                }
            }
        }
        base += 16; first = false;
    }
    // lane c holds the COMPLETE sums for features 4c..4c+3 — no reduction.
    f16x4 h0, h1v, h2, h3;
#pragma unroll
    for (int i = 0; i < 4; ++i) {
        h0[i] = (_Float16)A0[i]; h1v[i] = (_Float16)A1[i];
        h2[i] = (_Float16)A2[i]; h3[i] = (_Float16)A3[i];
    }
    *reinterpret_cast<f16x4*>(aggr + c4)       = h0;
    *reinterpret_cast<f16x4*>(aggr + 64 + c4)  = h1v;
    *reinterpret_cast<f16x4*>(aggr + 128 + c4) = h2;
    *reinterpret_cast<f16x4*>(aggr + 192 + c4) = h3;
}

// ---------------- MFMA projection: 4 tiles per block, no epilogue fusion ----
#define TPB 4
template <typename OutT>
__global__ __launch_bounds__(256) void k_projm(
    const _Float16* __restrict__ agg, const _Float16* __restrict__ Wt,
    const float* __restrict__ B, OutT* __restrict__ out,
    int nTiles, int do_tanh)
{
    int tid = threadIdx.x, lane = tid & 63, wf = tid >> 6;
    int col = lane & 15, quad = lane >> 4;
    int f0 = wf * 16;

    f16x8 bfrag[4][2];
    float bias[4];
#pragma unroll
    for (int h = 0; h < 4; ++h) {
#pragma unroll
        for (int ks = 0; ks < 2; ++ks)
            bfrag[h][ks] = *reinterpret_cast<const f16x8*>(
                Wt + (h * 64 + f0 + col) * 64 + ks * 32 + quad * 8);
        bias[h] = B[h * 64 + f0 + col];
    }

#pragma unroll
    for (int i = 0; i < TPB; ++i) {
        int tile = blockIdx.x * TPB + i;
        if (tile >= nTiles) break;
        int n0 = tile * 16;
        const _Float16* ap = agg + (size_t)n0 * 256 + (size_t)col * 256 + quad * 8;
        f32x4 acc = {0.f, 0.f, 0.f, 0.f};
#pragma unroll
        for (int h = 0; h < 4; ++h) {
            f16x8 a0 = *reinterpret_cast<const f16x8*>(ap + h * 64);
            f16x8 a1 = *reinterpret_cast<const f16x8*>(ap + h * 64 + 32);
            f32x4 dd = {0.f, 0.f, 0.f, 0.f};
            dd = __builtin_amdgcn_mfma_f32_16x16x32_f16(a0, bfrag[h][0], dd, 0, 0, 0);
            dd = __builtin_amdgcn_mfma_f32_16x16x32_f16(a1, bfrag[h][1], dd, 0, 0, 0);
            if (do_tanh) {
#pragma unroll
                for (int r = 0; r < 4; ++r) acc[r] += ftanh(dd[r] + bias[h]);
            } else {
#pragma unroll
                for (int r = 0; r < 4; ++r) acc[r] += dd[r] + bias[h];
            }
        }
#pragma unroll
        for (int r = 0; r < 4; ++r)
            out[(size_t)(n0 + quad * 4 + r) * 64 + f0 + col] = (OutT)(0.25f * acc[r]);
    }
}

// ---------------- launch -------------------
extern "C" void kernel_launch(void* const* d_in, const int* in_sizes, int n_in,
                              void* d_out, int out_size, void* d_ws, size_t ws_size,
                              hipStream_t stream) {
    const float* x   = (const float*)d_in[0];
    const int*   src = (const int*)d_in[1];
    const int*   dst = (const int*)d_in[2];
    const float* W1  = (const float*)d_in[3];
    const float* al1 = (const float*)d_in[4];
    const float* ar1 = (const float*)d_in[5];
    const float* b1  = (const float*)d_in[6];
    const float* W2  = (const float*)d_in[7];
    const float* al2 = (const float*)d_in[8];
    const float* ar2 = (const float*)d_in[9];
    const float* b2  = (const float*)d_in[10];
    float* out = (float*)d_out;

    int N_ = in_sizes[0] / 64;
    int E_ = in_sizes[1];
    int NB_ = (N_ + 255) >> 8;   // buckets of 256 nodes

    char* ws = (char*)d_ws;
    size_t off = 0;
    auto alloc = [&](size_t bytes) -> void* {
        void* p = ws + off;
        off = (off + bytes + 255) & ~(size_t)255;
        return p;
    };
    _Float16* agg = (_Float16*)alloc(((size_t)N_ + 16) * 256 * 2);
    _Float16* xh  = (_Float16*)alloc(((size_t)N_ + 16) * 64 * 2);
    _Float16* h1h = (_Float16*)alloc(((size_t)N_ + 16) * 64 * 2);
    float* el   = (float*)alloc(((size_t)N_ + 16) * 4 * 4);
    float* er   = (float*)alloc(((size_t)N_ + 16) * 4 * 4);
    int*   cnt  = (int*)alloc((size_t)(N_ + 16) * 4);
    int*   offs = (int*)alloc((size_t)(N_ + 1) * 4);
    int*   esrc = (int*)alloc((size_t)E_ * 4);
    unsigned* ebkt = (unsigned*)alloc((size_t)E_ * 4);
    int*   bktc = (int*)alloc((size_t)MAXNB * PADB * 4);
    int*   bcur = (int*)alloc((size_t)MAXNB * PADB * 4);
    int*   bbase= (int*)alloc((size_t)(MAXNB + 1) * 4);
    int*   bsums= (int*)alloc(4096);
    float* A1l  = (float*)alloc(64 * 4 * 4);
    float* A1r  = (float*)alloc(64 * 4 * 4);
    float* A2l  = (float*)alloc(64 * 4 * 4);
    float* A2r  = (float*)alloc(64 * 4 * 4);
    _Float16* Wt1 = (_Float16*)alloc(256 * 64 * 2);
    _Float16* Wt2 = (_Float16*)alloc(256 * 64 * 2);

    // prep (Al/Ar + Wt for both layers) + bucket-counter zeroing
    k_wprep<<<3, 256, 0, stream>>>(W1, al1, ar1, W2, al2, ar2,
                                   A1l, A1r, A2l, A2r, Wt1, Wt2, bktc, NB_);

    int hb = (E_ + TILE_A - 1) / TILE_A;      // bucket-hist blocks
    int nb16 = (N_ + 15) / 16;
    // fused bucket-hist + layer-1 el/er (+ fp16 x copy)
    k_elr_hist<<<hb + nb16, 256, 0, stream>>>(x, xh, A1l, A1r, el, er, N_,
                                              dst, bktc, E_, hb, NB_);
    k_bscan<<<1, 64, 0, stream>>>(bktc, bbase, bcur, NB_);
    k_binA<<<hb, 256, 0, stream>>>(src, dst, bcur, ebkt, E_, NB_);
    k_binC<<<NB_, 256, 0, stream>>>(ebkt, bbase, cnt, N_);
    int nchunks = (N_ + SC_CHUNK - 1) / SC_CHUNK;
    k_chunk_sums<<<nchunks, 256, 0, stream>>>(cnt, bsums, N_);
    k_scan_mid<<<1, 64, 0, stream>>>(bsums, nchunks);
    k_scan_write<<<nchunks, 256, 0, stream>>>(cnt, bsums, offs, N_);
    k_binB<<<NB_, 256, 0, stream>>>(ebkt, bbase, offs, esrc, N_);

    int nTiles = (N_ + 15) / 16;   // N=100000 -> 6250 exact
    int pgrid = (nTiles + TPB - 1) / TPB;
    // layer 1
    k_sg<<<nb16, 256, 0, stream>>>(esrc, offs, el, er, xh, agg, N_);
    k_projm<_Float16><<<pgrid, 256, 0, stream>>>(agg, Wt1, b1, h1h, nTiles, 1);
    // layer 2 el/er from fp16 h1, then gather + proj
    k_elr2<<<nb16, 256, 0, stream>>>(h1h, A2l, A2r, el, er, N_);
    k_sg<<<nb16, 256, 0, stream>>>(esrc, offs, el, er, h1h, agg, N_);
    k_projm<float><<<pgrid, 256, 0, stream>>>(agg, Wt2, b2, out, nTiles, 0);
}

// Round 2
// 276.648 us; speedup vs baseline: 1.3701x; 1.1307x over previous
//
#include <hip/hip_runtime.h>

typedef _Float16 f16x8 __attribute__((ext_vector_type(8)));
typedef _Float16 f16x4 __attribute__((ext_vector_type(4)));
typedef float f32x4 __attribute__((ext_vector_type(4)));

#define PADB 16     // pad bucket counters: one per 64B line
#define MAXNB 512   // max buckets (N <= 131072, bucket = 256 nodes)
#define TILE_A 4096 // edges per binning tile

__device__ __forceinline__ float lrelu(float v) { return v >= 0.f ? v : 0.2f * v; }
// clamped exp: identical softmax ratios unless logits >60 (never for this data)
__device__ __forceinline__ float cexp(float v) { return expf(fminf(v, 60.f)); }
// fast tanh: (e^2x-1)/(e^2x+1); clamp avoids overflow, e->0 handles -inf side
__device__ __forceinline__ float ftanh(float x) {
    float e = __expf(fminf(2.f * x, 30.f));
    return (e - 1.f) / (e + 1.f);
}

// ---- fused prep: blocks 0,1 build Al/Ar + Wt fp16 per layer; block 2 zeros
// the (tiny, padded) bucket counters ----------------------------------------
__global__ __launch_bounds__(256) void k_wprep(
    const float* __restrict__ W1, const float* __restrict__ al1, const float* __restrict__ ar1,
    const float* __restrict__ W2, const float* __restrict__ al2, const float* __restrict__ ar2,
    float* __restrict__ A1l, float* __restrict__ A1r,
    float* __restrict__ A2l, float* __restrict__ A2r,
    _Float16* __restrict__ Wt1, _Float16* __restrict__ Wt2,
    int* __restrict__ bktc, int nb)
{
    int b = blockIdx.x, t = threadIdx.x;
    if (b < 2) {
        const float* W  = b ? W2 : W1;
        const float* al = b ? al2 : al1;
        const float* ar = b ? ar2 : ar1;
        float* Al = b ? A2l : A1l;
        float* Ar = b ? A2r : A1r;
        _Float16* Wt = b ? Wt2 : Wt1;
        int k = t >> 2, h = t & 3;
        float sl = 0.f, sr = 0.f;
#pragma unroll 8
        for (int f = 0; f < 64; ++f) {
            float wv = W[k * 256 + h * 64 + f];
            sl = fmaf(wv, al[h * 64 + f], sl);
            sr = fmaf(wv, ar[h * 64 + f], sr);
        }
        Al[k * 4 + h] = sl;
        Ar[k * 4 + h] = sr;
        int col = t;
#pragma unroll 8
        for (int kk = 0; kk < 64; ++kk)
            Wt[col * 64 + kk] = (_Float16)W[kk * 256 + col];
    } else {
        for (int i = t; i < nb; i += 256) bktc[(size_t)i * PADB] = 0;
    }
}

// ---- fused: blocks [0,eb) LDS bucket-histogram of dst; rest: layer-1 el/er -
__global__ __launch_bounds__(256) void k_elr_hist(
    const float* __restrict__ Xf, _Float16* __restrict__ XhOut,
    const float* __restrict__ Al, const float* __restrict__ Ar,
    float* __restrict__ el, float* __restrict__ er, int nNodes,
    const int* __restrict__ dst, int* __restrict__ bktc, int E_, int ebBlocks,
    int nb)
{
    int b = blockIdx.x;
    if (b < ebBlocks) {
        __shared__ int lb[MAXNB];
        int t = threadIdx.x;
        for (int i = t; i < nb; i += 256) lb[i] = 0;
        __syncthreads();
        int base = b * TILE_A;
        int end = base + TILE_A; if (end > E_) end = E_;
        for (int j = base + t; j < end; j += 256)
            atomicAdd(&lb[((unsigned)dst[j]) >> 8], 1);
        __syncthreads();
        for (int i = t; i < nb; i += 256) {
            int c = lb[i];
            if (c) atomicAdd(&bktc[(size_t)i * PADB], c);
        }
        return;
    }
    int lane = threadIdx.x & 63, wid = threadIdx.x >> 6;
    int q = lane >> 4, c = lane & 15;
    int n = (b - ebBlocks) * 16 + wid * 4 + q;
    if (n >= nNodes) return;  // uniform within each 16-lane quarter
    float4 xv = *reinterpret_cast<const float4*>(Xf + (size_t)n * 64 + c * 4);
    f16x4 xh4 = {(_Float16)xv.x, (_Float16)xv.y, (_Float16)xv.z, (_Float16)xv.w};
    *reinterpret_cast<f16x4*>(XhOut + (size_t)n * 64 + c * 4) = xh4;
    float p0 = 0.f, p1 = 0.f, p2 = 0.f, p3 = 0.f;
    float q0 = 0.f, q1 = 0.f, q2 = 0.f, q3 = 0.f;
    float xs[4] = {xv.x, xv.y, xv.z, xv.w};
#pragma unroll
    for (int i = 0; i < 4; ++i) {
        float4 av = *reinterpret_cast<const float4*>(Al + (c * 4 + i) * 4);
        float4 rv = *reinterpret_cast<const float4*>(Ar + (c * 4 + i) * 4);
        p0 = fmaf(xs[i], av.x, p0); p1 = fmaf(xs[i], av.y, p1);
        p2 = fmaf(xs[i], av.z, p2); p3 = fmaf(xs[i], av.w, p3);
        q0 = fmaf(xs[i], rv.x, q0); q1 = fmaf(xs[i], rv.y, q1);
        q2 = fmaf(xs[i], rv.z, q2); q3 = fmaf(xs[i], rv.w, q3);
    }
#pragma unroll
    for (int m = 1; m <= 8; m <<= 1) {
        p0 += __shfl_xor(p0, m, 64); p1 += __shfl_xor(p1, m, 64);
        p2 += __shfl_xor(p2, m, 64); p3 += __shfl_xor(p3, m, 64);
        q0 += __shfl_xor(q0, m, 64); q1 += __shfl_xor(q1, m, 64);
        q2 += __shfl_xor(q2, m, 64); q3 += __shfl_xor(q3, m, 64);
    }
    if (c == 0) {
        *reinterpret_cast<float4*>(el + (size_t)n * 4) = make_float4(p0, p1, p2, p3);
        *reinterpret_cast<float4*>(er + (size_t)n * 4) = make_float4(q0, q1, q2, q3);
    }
}

// ---- layer-2 el/er from fp16 h1, quarter-wave per node --------------------
__global__ __launch_bounds__(256) void k_elr2(
    const _Float16* __restrict__ Xh,
    const float* __restrict__ Al, const float* __restrict__ Ar,
    float* __restrict__ el, float* __restrict__ er, int nNodes)
{
    int lane = threadIdx.x & 63, wid = threadIdx.x >> 6;
    int q = lane >> 4, c = lane & 15;
    int n = blockIdx.x * 16 + wid * 4 + q;
    if (n >= nNodes) return;
    f16x4 xh4 = *reinterpret_cast<const f16x4*>(Xh + (size_t)n * 64 + c * 4);
    float p0 = 0.f, p1 = 0.f, p2 = 0.f, p3 = 0.f;
    float q0 = 0.f, q1 = 0.f, q2 = 0.f, q3 = 0.f;
#pragma unroll
    for (int i = 0; i < 4; ++i) {
        float xs = (float)xh4[i];
        float4 av = *reinterpret_cast<const float4*>(Al + (c * 4 + i) * 4);
        float4 rv = *reinterpret_cast<const float4*>(Ar + (c * 4 + i) * 4);
        p0 = fmaf(xs, av.x, p0); p1 = fmaf(xs, av.y, p1);
        p2 = fmaf(xs, av.z, p2); p3 = fmaf(xs, av.w, p3);
        q0 = fmaf(xs, rv.x, q0); q1 = fmaf(xs, rv.y, q1);
        q2 = fmaf(xs, rv.z, q2); q3 = fmaf(xs, rv.w, q3);
    }
#pragma unroll
    for (int m = 1; m <= 8; m <<= 1) {
        p0 += __shfl_xor(p0, m, 64); p1 += __shfl_xor(p1, m, 64);
        p2 += __shfl_xor(p2, m, 64); p3 += __shfl_xor(p3, m, 64);
        q0 += __shfl_xor(q0, m, 64); q1 += __shfl_xor(q1, m, 64);
        q2 += __shfl_xor(q2, m, 64); q3 += __shfl_xor(q3, m, 64);
    }
    if (c == 0) {
        *reinterpret_cast<float4*>(el + (size_t)n * 4) = make_float4(p0, p1, p2, p3);
        *reinterpret_cast<float4*>(er + (size_t)n * 4) = make_float4(q0, q1, q2, q3);
    }
}

// ---- single-wave exclusive scan of bucket counts -> bases + cursors -------
__global__ void k_bscan(const int* __restrict__ bktc, int* __restrict__ bbase,
                        int* __restrict__ bcur, int nb) {
    int lane = threadIdx.x;
    int carry = 0;
    for (int base = 0; base < nb; base += 64) {
        int i = base + lane;
        int v = (i < nb) ? bktc[(size_t)i * PADB] : 0;
        int sc = v;
#pragma unroll
        for (int d = 1; d < 64; d <<= 1) {
            int u = __shfl_up(sc, d, 64);
            if (lane >= d) sc += u;
        }
        if (i < nb) {
            int ex = carry + sc - v;
            bbase[i] = ex;
            bcur[(size_t)i * PADB] = ex;
        }
        carry += __shfl(sc, 63, 64);
    }
    if (lane == 0) bbase[nb] = carry;
}

// ---- binA: partition edges into dst>>8 buckets, LDS-staged for coalescing -
// packs (src | dstlo<<17); valid while N < 131072
__global__ __launch_bounds__(256) void k_binA(
    const int* __restrict__ src, const int* __restrict__ dst,
    int* __restrict__ bcur, unsigned* __restrict__ ebkt, int E_, int nb)
{
    __shared__ int lcnt[MAXNB];
    __shared__ int lcur[MAXNB];
    __shared__ int lofs[MAXNB];
    __shared__ int gbase[MAXNB];
    __shared__ unsigned spack[TILE_A];
    __shared__ int gposs[TILE_A];
    int t = threadIdx.x;
    int tile0 = blockIdx.x * TILE_A;
    int cntT = E_ - tile0; if (cntT > TILE_A) cntT = TILE_A;

    for (int i = t; i < nb; i += 256) { lcnt[i] = 0; lcur[i] = 0; }
    __syncthreads();

    int myS[16], myD[16];
#pragma unroll
    for (int k = 0; k < 16; ++k) {
        int idx = k * 256 + t;
        if (idx < cntT) {
            myS[k] = src[tile0 + idx];
            myD[k] = dst[tile0 + idx];
            atomicAdd(&lcnt[((unsigned)myD[k]) >> 8], 1);
        }
    }
    __syncthreads();

    // reserve output space per bucket (one global atomic per tile x bucket)
    for (int i = t; i < nb; i += 256) {
        int c = lcnt[i];
        gbase[i] = c ? atomicAdd(&bcur[(size_t)i * PADB], c) : 0;
    }
    // exclusive scan of lcnt -> lofs (wave 0)
    if (t < 64) {
        int carry = 0;
        for (int base = 0; base < nb; base += 64) {
            int i = base + t;
            int v = (i < nb) ? lcnt[i] : 0;
            int sc = v;
#pragma unroll
            for (int d = 1; d < 64; d <<= 1) {
                int u = __shfl_up(sc, d, 64);
                if (t >= d) sc += u;
            }
            if (i < nb) lofs[i] = carry + sc - v;
            carry += __shfl(sc, 63, 64);
        }
    }
    __syncthreads();

    // group the tile's edges by bucket in LDS, remember global dest
#pragma unroll
    for (int k = 0; k < 16; ++k) {
        int idx = k * 256 + t;
        if (idx < cntT) {
            int b = ((unsigned)myD[k]) >> 8;
            int slot = atomicAdd(&lcur[b], 1);
            int lidx = lofs[b] + slot;
            spack[lidx] = (unsigned)myS[k] | (((unsigned)myD[k] & 255u) << 17);
            gposs[lidx] = gbase[b] + slot;
        }
    }
    __syncthreads();

    // write out: consecutive staged entries -> consecutive global addresses
    for (int j = t; j < cntT; j += 256)
        ebkt[gposs[j]] = spack[j];
}

// ---- binC: per-bucket node-degree counts (plain writes, no global atomics) -
__global__ __launch_bounds__(256) void k_binC(
    const unsigned* __restrict__ ebkt, const int* __restrict__ bbase,
    int* __restrict__ cnt, int nNodes)
{
    __shared__ int lc[256];
    int b = blockIdx.x, t = threadIdx.x;
    lc[t] = 0;
    __syncthreads();
    int s0 = bbase[b], s1 = bbase[b + 1];
    for (int j = s0 + t; j < s1; j += 256)
        atomicAdd(&lc[ebkt[j] >> 17], 1);
    __syncthreads();
    int node = (b << 8) + t;
    if (node < nNodes) cnt[node] = lc[t];
}

// ---- binB: final in-bucket scatter; writes land in a ~10KB hot window -----
__global__ __launch_bounds__(256) void k_binB(
    const unsigned* __restrict__ ebkt, const int* __restrict__ bbase,
    const int* __restrict__ offs, int* __restrict__ esrc, int nNodes)
{
    __shared__ int lcur[256];
    __shared__ int lofs[256];
    int b = blockIdx.x, t = threadIdx.x;
    lcur[t] = 0;
    int node = (b << 8) + t;
    lofs[t] = (node < nNodes) ? offs[node] : 0;
    __syncthreads();
    int s0 = bbase[b], s1 = bbase[b + 1];
    for (int j = s0 + t; j < s1; j += 256) {
        unsigned v = ebkt[j];
        int dl = v >> 17;
        int p = lofs[dl] + atomicAdd(&lcur[dl], 1);
        esrc[p] = (int)(v & 0x1FFFFu);
    }
}

// ---------------- CSR scan (unpadded cnt) -------------------
#define SC_VPT 8
#define SC_CHUNK 2048  // 256 threads * 8

__global__ __launch_bounds__(256) void k_chunk_sums(const int* __restrict__ cnt,
                                                    int* __restrict__ bsums, int n) {
    int tid = threadIdx.x;
    int base = blockIdx.x * SC_CHUNK + tid * SC_VPT;
    int s = 0;
#pragma unroll
    for (int i = 0; i < SC_VPT; ++i) { int idx = base + i; if (idx < n) s += cnt[idx]; }
#pragma unroll
    for (int m = 1; m < 64; m <<= 1) s += __shfl_xor(s, m, 64);
    int lane = tid & 63, wid = tid >> 6;
    __shared__ int sh[4];
    if (lane == 0) sh[wid] = s;
    __syncthreads();
    if (tid == 0) bsums[blockIdx.x] = sh[0] + sh[1] + sh[2] + sh[3];
}

// wave-parallel exclusive scan of bsums
__global__ void k_scan_mid(int* bsums, int nb) {
    int lane = threadIdx.x & 63;
    int carry = 0;
    for (int base = 0; base < nb; base += 64) {
        int i = base + lane;
        int v = (i < nb) ? bsums[i] : 0;
        int sc = v;
#pragma unroll
        for (int d = 1; d < 64; d <<= 1) {
            int t = __shfl_up(sc, d, 64);
            if (lane >= d) sc += t;
        }
        if (i < nb) bsums[i] = carry + sc - v;
        carry += __shfl(sc, 63, 64);
    }
}

__global__ __launch_bounds__(256) void k_scan_write(const int* __restrict__ cnt,
                                                    const int* __restrict__ bsums,
                                                    int* __restrict__ offs, int n) {
    int tid = threadIdx.x;
    int base = blockIdx.x * SC_CHUNK + tid * SC_VPT;
    int v[SC_VPT]; int s = 0;
#pragma unroll
    for (int i = 0; i < SC_VPT; ++i) { int idx = base + i; v[i] = (idx < n) ? cnt[idx] : 0; s += v[i]; }
    int lane = tid & 63, wid = tid >> 6;
    int sc = s;
#pragma unroll
    for (int d = 1; d < 64; d <<= 1) { int t = __shfl_up(sc, d, 64); if (lane >= d) sc += t; }
    __shared__ int wsum[4];
    if (lane == 63) wsum[wid] = sc;
    __syncthreads();
    int wbase = 0;
    for (int i = 0; i < wid; ++i) wbase += wsum[i];
    int p = bsums[blockIdx.x] + wbase + (sc - s);
#pragma unroll
    for (int i = 0; i < SC_VPT; ++i) {
        int idx = base + i;
        if (idx < n) {
            offs[idx] = p; p += v[i];
            if (idx == n - 1) offs[n] = p;
        }
    }
}

// ---- FUSED softmax-stats + gather + MFMA projection ------------------------
// One block = 16 nodes = exactly one MFMA tile. The gathered 16x256 f16 tile
// lives in LDS (stride 264 f16 = 528B -> ~2-way bank alias on column reads,
// which is free) instead of round-tripping 51.2MB/layer through HBM.
template <typename OutT>
__global__ __launch_bounds__(256) void k_sgp(
    const int* __restrict__ esrc, const int* __restrict__ offs,
    const float* __restrict__ el, const float* __restrict__ er,
    const _Float16* __restrict__ Xh,
    const _Float16* __restrict__ Wt, const float* __restrict__ B,
    OutT* __restrict__ out, int nNodes, int do_tanh)
{
    __shared__ _Float16 sagg[16 * 264];
    int tid = threadIdx.x;
    int lane = tid & 63, wid = tid >> 6;
    int q = lane >> 4, c = lane & 15, c4 = c * 4;
    int n = blockIdx.x * 16 + wid * 4 + q;
    int nl = wid * 4 + q;
    bool valid = n < nNodes;

    float A0[4] = {}, A1[4] = {}, A2[4] = {}, A3[4] = {};
    if (valid) {
        int s0 = offs[n], s1 = offs[n + 1];
        int d = s1 - s0;
        float4 erv = *reinterpret_cast<const float4*>(er + (size_t)n * 4);

        // ---- stats (no max-pass): chunk 0 (16 edges) cached in registers ----
        int sreg = 0;
        float x0 = 0.f, x1 = 0.f, x2 = 0.f, x3 = 0.f;
        if (c < d) {
            sreg = esrc[s0 + c];
            float4 v = *reinterpret_cast<const float4*>(el + (size_t)sreg * 4);
            x0 = cexp(lrelu(v.x + erv.x)); x1 = cexp(lrelu(v.y + erv.y));
            x2 = cexp(lrelu(v.z + erv.z)); x3 = cexp(lrelu(v.w + erv.w));
        }
        float t0 = x0, t1 = x1, t2 = x2, t3 = x3;
        for (int j = s0 + c + 16; j < s1; j += 16) {   // deg > 16 (rare)
            int s = esrc[j];
            float4 v = *reinterpret_cast<const float4*>(el + (size_t)s * 4);
            t0 += cexp(lrelu(v.x + erv.x)); t1 += cexp(lrelu(v.y + erv.y));
            t2 += cexp(lrelu(v.z + erv.z)); t3 += cexp(lrelu(v.w + erv.w));
        }
#pragma unroll
        for (int m = 1; m <= 8; m <<= 1) {   // reduce within quarter
            t0 += __shfl_xor(t0, m, 64); t1 += __shfl_xor(t1, m, 64);
            t2 += __shfl_xor(t2, m, 64); t3 += __shfl_xor(t3, m, 64);
        }
        float i0 = 1.f / t0, i1 = 1.f / t1, i2 = 1.f / t2, i3 = 1.f / t3;
        float a0 = x0 * i0, a1 = x1 * i1, a2 = x2 * i2, a3 = x3 * i3;

        // ---- gather: chunks of 16 edges; rounds of 4 edges, 4 indep loads ----
        int base = s0;
        bool first = true;
        while (base < s1) {
            int cnt_ = s1 - base; if (cnt_ > 16) cnt_ = 16;
            int sj; float w0, w1, w2, w3;
            if (first) { sj = sreg; w0 = a0; w1 = a1; w2 = a2; w3 = a3; }
            else {
                sj = 0; w0 = w1 = w2 = w3 = 0.f;
                if (c < cnt_) {
                    sj = esrc[base + c];
                    float4 v = *reinterpret_cast<const float4*>(el + (size_t)sj * 4);
                    w0 = cexp(lrelu(v.x + erv.x)) * i0;
                    w1 = cexp(lrelu(v.y + erv.y)) * i1;
                    w2 = cexp(lrelu(v.z + erv.z)) * i2;
                    w3 = cexp(lrelu(v.w + erv.w)) * i3;
                }
            }
            int rnd = (cnt_ + 3) & ~3;
            for (int b = 0; b < rnd; b += 4) {
                int ss[4];
                float q0[4], q1[4], q2[4], q3[4];
                f16x4 xv[4];
#pragma unroll
                for (int u = 0; u < 4; ++u) {
                    int jj = q * 16 + b + u;         // lane holding edge b+u
                    ss[u] = __shfl(sj, jj, 64);
                    q0[u] = __shfl(w0, jj, 64); q1[u] = __shfl(w1, jj, 64);
                    q2[u] = __shfl(w2, jj, 64); q3[u] = __shfl(w3, jj, 64);
                }
#pragma unroll
                for (int u = 0; u < 4; ++u)
                    xv[u] = *reinterpret_cast<const f16x4*>(Xh + (size_t)ss[u] * 64 + c4);
#pragma unroll
                for (int u = 0; u < 4; ++u) {
#pragma unroll
                    for (int i = 0; i < 4; ++i) {
                        float xf = (float)xv[u][i];
                        A0[i] = fmaf(q0[u], xf, A0[i]);
                        A1[i] = fmaf(q1[u], xf, A1[i]);
                        A2[i] = fmaf(q2[u], xf, A2[i]);
                        A3[i] = fmaf(q3[u], xf, A3[i]);
                    }
                }
            }
            base += 16; first = false;
        }
    }
    // lane c holds COMPLETE sums for features 4c..4c+3 of heads 0..3
    {
        _Float16* aggr = sagg + nl * 264;
        f16x4 h0, h1v, h2, h3;
#pragma unroll
        for (int i = 0; i < 4; ++i) {
            h0[i] = (_Float16)A0[i]; h1v[i] = (_Float16)A1[i];
            h2[i] = (_Float16)A2[i]; h3[i] = (_Float16)A3[i];
        }
        *reinterpret_cast<f16x4*>(aggr + c4)       = h0;
        *reinterpret_cast<f16x4*>(aggr + 64 + c4)  = h1v;
        *reinterpret_cast<f16x4*>(aggr + 128 + c4) = h2;
        *reinterpret_cast<f16x4*>(aggr + 192 + c4) = h3;
    }

    // weight fragments (L2-resident 32KB, loaded post-gather to keep VGPRs low)
    int col = c, quad = q, f0 = wid * 16;
    f16x8 bfrag[4][2];
    float bias[4];
#pragma unroll
    for (int h = 0; h < 4; ++h) {
#pragma unroll
        for (int ks = 0; ks < 2; ++ks)
            bfrag[h][ks] = *reinterpret_cast<const f16x8*>(
                Wt + (h * 64 + f0 + col) * 64 + ks * 32 + quad * 8);
        bias[h] = B[h * 64 + f0 + col];
    }
    __syncthreads();

    // ---- projection: 8 MFMAs per wave straight out of LDS ----
    const _Float16* ap = sagg + col * 264 + quad * 8;
    f32x4 acc = {0.f, 0.f, 0.f, 0.f};
#pragma unroll
    for (int h = 0; h < 4; ++h) {
        f16x8 a0 = *reinterpret_cast<const f16x8*>(ap + h * 64);
        f16x8 a1 = *reinterpret_cast<const f16x8*>(ap + h * 64 + 32);
        f32x4 dd = {0.f, 0.f, 0.f, 0.f};
        dd = __builtin_amdgcn_mfma_f32_16x16x32_f16(a0, bfrag[h][0], dd, 0, 0, 0);
        dd = __builtin_amdgcn_mfma_f32_16x16x32_f16(a1, bfrag[h][1], dd, 0, 0, 0);
        if (do_tanh) {
#pragma unroll
            for (int r = 0; r < 4; ++r) acc[r] += ftanh(dd[r] + bias[h]);
        } else {
#pragma unroll
            for (int r = 0; r < 4; ++r) acc[r] += dd[r] + bias[h];
        }
    }
    int n0 = blockIdx.x * 16;
#pragma unroll
    for (int r = 0; r < 4; ++r) {
        int row = n0 + quad * 4 + r;
        if (row < nNodes)
            out[(size_t)row * 64 + f0 + col] = (OutT)(0.25f * acc[r]);
    }
}

// ---------------- launch -------------------
extern "C" void kernel_launch(void* const* d_in, const int* in_sizes, int n_in,
                              void* d_out, int out_size, void* d_ws, size_t ws_size,
                              hipStream_t stream) {
    const float* x   = (const float*)d_in[0];
    const int*   src = (const int*)d_in[1];
    const int*   dst = (const int*)d_in[2];
    const float* W1  = (const float*)d_in[3];
    const float* al1 = (const float*)d_in[4];
    const float* ar1 = (const float*)d_in[5];
    const float* b1  = (const float*)d_in[6];
    const float* W2  = (const float*)d_in[7];
    const float* al2 = (const float*)d_in[8];
    const float* ar2 = (const float*)d_in[9];
    const float* b2  = (const float*)d_in[10];
    float* out = (float*)d_out;

    int N_ = in_sizes[0] / 64;
    int E_ = in_sizes[1];
    int NB_ = (N_ + 255) >> 8;   // buckets of 256 nodes

    char* ws = (char*)d_ws;
    size_t off = 0;
    auto alloc = [&](size_t bytes) -> void* {
        void* p = ws + off;
        off = (off + bytes + 255) & ~(size_t)255;
        return p;
    };
    _Float16* xh  = (_Float16*)alloc(((size_t)N_ + 16) * 64 * 2);
    _Float16* h1h = (_Float16*)alloc(((size_t)N_ + 16) * 64 * 2);
    float* el   = (float*)alloc(((size_t)N_ + 16) * 4 * 4);
    float* er   = (float*)alloc(((size_t)N_ + 16) * 4 * 4);
    int*   cnt  = (int*)alloc((size_t)(N_ + 16) * 4);
    int*   offs = (int*)alloc((size_t)(N_ + 1) * 4);
    int*   esrc = (int*)alloc((size_t)E_ * 4);
    unsigned* ebkt = (unsigned*)alloc((size_t)E_ * 4);
    int*   bktc = (int*)alloc((size_t)MAXNB * PADB * 4);
    int*   bcur = (int*)alloc((size_t)MAXNB * PADB * 4);
    int*   bbase= (int*)alloc((size_t)(MAXNB + 1) * 4);
    int*   bsums= (int*)alloc(4096);
    float* A1l  = (float*)alloc(64 * 4 * 4);
    float* A1r  = (float*)alloc(64 * 4 * 4);
    float* A2l  = (float*)alloc(64 * 4 * 4);
    float* A2r  = (float*)alloc(64 * 4 * 4);
    _Float16* Wt1 = (_Float16*)alloc(256 * 64 * 2);
    _Float16* Wt2 = (_Float16*)alloc(256 * 64 * 2);

    // prep (Al/Ar + Wt for both layers) + bucket-counter zeroing
    k_wprep<<<3, 256, 0, stream>>>(W1, al1, ar1, W2, al2, ar2,
                                   A1l, A1r, A2l, A2r, Wt1, Wt2, bktc, NB_);

    int hb = (E_ + TILE_A - 1) / TILE_A;      // bucket-hist blocks
    int nb16 = (N_ + 15) / 16;
    // fused bucket-hist + layer-1 el/er (+ fp16 x copy)
    k_elr_hist<<<hb + nb16, 256, 0, stream>>>(x, xh, A1l, A1r, el, er, N_,
                                              dst, bktc, E_, hb, NB_);
    k_bscan<<<1, 64, 0, stream>>>(bktc, bbase, bcur, NB_);
    k_binA<<<hb, 256, 0, stream>>>(src, dst, bcur, ebkt, E_, NB_);
    k_binC<<<NB_, 256, 0, stream>>>(ebkt, bbase, cnt, N_);
    int nchunks = (N_ + SC_CHUNK - 1) / SC_CHUNK;
    k_chunk_sums<<<nchunks, 256, 0, stream>>>(cnt, bsums, N_);
    k_scan_mid<<<1, 64, 0, stream>>>(bsums, nchunks);
    k_scan_write<<<nchunks, 256, 0, stream>>>(cnt, bsums, offs, N_);
    k_binB<<<NB_, 256, 0, stream>>>(ebkt, bbase, offs, esrc, N_);

    // layer 1: fused gather + projection (tanh), fp16 out
    k_sgp<_Float16><<<nb16, 256, 0, stream>>>(esrc, offs, el, er, xh,
                                              Wt1, b1, h1h, N_, 1);
    // layer 2 el/er from fp16 h1, then fused gather + projection, fp32 out
    k_elr2<<<nb16, 256, 0, stream>>>(h1h, A2l, A2r, el, er, N_);
    k_sgp<float><<<nb16, 256, 0, stream>>>(esrc, offs, el, er, h1h,
                                           Wt2, b2, out, N_, 0);
}